// Round 14
// baseline (72.591 us; speedup 1.0000x reference)
//
#include <hip/hip_runtime.h>

#define NV 1448
#define JD 4344    // 3*NV
#define CC 256
#define BB 64
#define QQ 128     // 2*BB
#define QCOLS 362  // NV/4, columns per chamfer block
#define NROW (2 * BB * NV)  // 185344 row-slots (dir x b x row)

// ---------------------------------------------------------------------------
// K1: global average pool over H*W=64 -> latT[c][q], q = t*64+b.
// Thread 0 zeroes the combine accumulator. (R11 version, proven.)
// ---------------------------------------------------------------------------
__global__ __launch_bounds__(256) void pool_kernel(const float* __restrict__ inp,
                                                   const float* __restrict__ tgt,
                                                   float* __restrict__ latT,
                                                   unsigned long long* __restrict__ acc) {
    int gid  = blockIdx.x * 256 + threadIdx.x;
    if (gid == 0) { acc[0] = 0ull; acc[1] = 0ull; }
    int lane = gid & 15;
    int row  = gid >> 4;                          // (t,b,c) flat, 32768 rows
    if (row >= 2 * BB * CC) return;
    int t  = row >> 14;                           // BB*CC = 16384
    int bc = row & 16383;
    const float* src = (t ? tgt : inp) + (size_t)bc * 64;
    float4 v = reinterpret_cast<const float4*>(src)[lane];
    float s = (v.x + v.y) + (v.z + v.w);
    s += __shfl_xor(s, 1);
    s += __shfl_xor(s, 2);
    s += __shfl_xor(s, 4);
    s += __shfl_xor(s, 8);
    if (lane == 0) {
        int b = bc >> 8, c = bc & 255;
        latT[c * QQ + t * BB + b] = s * (1.0f / 64.0f);
    }
}

// ---------------------------------------------------------------------------
// K2: decode GEMM v6 = R12's K-split-across-waves geometry, repaired:
//  - NO min-waves launch_bounds cap (R12's VGPR=64 cap caused total spill);
//    occupancy comes from LDS: 51.2KB/block -> 3 blocks/CU = 12 waves/CU
//    = 3 waves/SIMD (vs 1/SIMD in R5/R11 -> latency exposed).
//  - Padded, 16B-aligned LDS strides: AsT[32][20], Bs[32][80]
//    (R12's unpadded scatter was an 8-way write conflict, 975K counted).
// grid (272 jt, 2 L, 2 qh) x 256 thr; block = 16j x 64q, K=256.
// Wave w owns k-chunks {32w, 32w+128} in a PRIVATE quarter: no main-loop
// barriers (same-wave lgkmcnt ordering only). Per thread 4j x 4q, 8 fma
// per ds_read_b128. Epilogue: one barrier + LDS cross-wave reduce.
// ---------------------------------------------------------------------------
__global__ __launch_bounds__(256) void decode_kernel(const float* __restrict__ latT,
                                                     const float* __restrict__ muL,
                                                     const float* __restrict__ deltaL,
                                                     const float* __restrict__ muR,
                                                     const float* __restrict__ deltaR,
                                                     const int* __restrict__ labels,
                                                     float* __restrict__ pts3) {
    const int jt = blockIdx.x;                 // 272 tiles of 16 j
    const int L  = blockIdx.y;
    const int qh = blockIdx.z;                 // q half: 64 q's
    const float* __restrict__ delta = L ? deltaR : deltaL;
    const float* __restrict__ mu    = L ? muR : muL;
    const int j0   = jt * 16;
    const int tid  = threadIdx.x;
    const int w    = tid >> 6;                 // wave 0..3
    const int lane = tid & 63;
    const int jl   = lane & 3;                 // 4 j-lanes x 4 j = 16 j
    const int qg   = lane >> 2;                // 16 q-lanes x 4 q = 64 q

    __shared__ float lds[4 * 3200];            // 51200 B total
    float* AsT = lds + w * 3200;               // [32][20] k-major, stride 20 (80B, 16B-aligned)
    float* Bs  = AsT + 640;                    // [32][80] k-major, stride 80 (320B, aligned)

    float acc[4][4];
#pragma unroll
    for (int u = 0; u < 4; ++u)
#pragma unroll
        for (int v = 0; v < 4; ++v) acc[u][v] = 0.f;

    const float4* latT4 = reinterpret_cast<const float4*>(latT);

#pragma unroll
    for (int c = 0; c < 2; ++c) {
        const int kc = w * 32 + c * 128;       // this wave's k-chunk
        // stage AsT: 16 j x 32 k = 128 float4, 2/lane (transposed scatter, 4-way worst)
#pragma unroll
        for (int it = 0; it < 2; ++it) {
            int idx = it * 64 + lane;
            int kq  = idx & 7;                 // float4-chunk of k
            int r   = idx >> 3;                // j row 0..15
            int j   = j0 + r;
            float4 v = make_float4(0.f, 0.f, 0.f, 0.f);
            if (j < JD)
                v = *reinterpret_cast<const float4*>(delta + (size_t)j * CC + kc + kq * 4);
            AsT[(kq * 4 + 0) * 20 + r] = v.x;
            AsT[(kq * 4 + 1) * 20 + r] = v.y;
            AsT[(kq * 4 + 2) * 20 + r] = v.z;
            AsT[(kq * 4 + 3) * 20 + r] = v.w;
        }
        // stage Bs: 32 k x 64 q = 512 float4 loads (coalesced along q), 8/lane
#pragma unroll
        for (int i = 0; i < 8; ++i) {
            int idx = i * 64 + lane;
            int qi  = idx & 15;
            int k   = idx >> 4;
            float4 v = latT4[(size_t)(kc + k) * 32 + qh * 16 + qi];
            Bs[k * 80 + qi * 4 + 0] = v.x;
            Bs[k * 80 + qi * 4 + 1] = v.y;
            Bs[k * 80 + qi * 4 + 2] = v.z;
            Bs[k * 80 + qi * 4 + 3] = v.w;
        }
        // compute (same-wave ds_write->ds_read: compiler inserts lgkmcnt)
#pragma unroll
        for (int k4 = 0; k4 < 32; k4 += 4) {
#pragma unroll
            for (int kk = 0; kk < 4; ++kk) {
                float4 a = *reinterpret_cast<const float4*>(&AsT[(k4 + kk) * 20 + jl * 4]);
                float4 b = *reinterpret_cast<const float4*>(&Bs[(k4 + kk) * 80 + qg * 4]);
                float av[4] = {a.x, a.y, a.z, a.w};
                float bv[4] = {b.x, b.y, b.z, b.w};
#pragma unroll
                for (int u = 0; u < 4; ++u)
#pragma unroll
                    for (int v = 0; v < 4; ++v)
                        acc[u][v] = fmaf(av[u], bv[v], acc[u][v]);
            }
        }
    }

    // cross-wave reduction: red4[lane*17 + w*4 + u] (17-f4 stride)
    __syncthreads();
    float4* red4 = reinterpret_cast<float4*>(lds);   // 64*17 f4 = 17408 B, fits
#pragma unroll
    for (int u = 0; u < 4; ++u)
        red4[lane * 17 + w * 4 + u] = make_float4(acc[u][0], acc[u][1], acc[u][2], acc[u][3]);
    __syncthreads();

    if (w == 0) {
#pragma unroll
        for (int u = 0; u < 4; ++u) {
#pragma unroll
            for (int ww = 1; ww < 4; ++ww) {
                float4 p = red4[lane * 17 + ww * 4 + u];
                acc[u][0] += p.x; acc[u][1] += p.y; acc[u][2] += p.z; acc[u][3] += p.w;
            }
        }
        int j = j0 + jl * 4;
        if (j + 3 < JD) {                      // JD%4==0: full quad or skip
            float4 m = *reinterpret_cast<const float4*>(mu + j);
#pragma unroll
            for (int v = 0; v < 4; ++v) {
                int q = qh * 64 + qg * 4 + v;
                int b = q & 63;
                if (labels[b] == L) {
                    float4 o = make_float4(acc[0][v] + m.x, acc[1][v] + m.y,
                                           acc[2][v] + m.z, acc[3][v] + m.w);
                    *reinterpret_cast<float4*>(pts3 + (size_t)q * JD + j) = o;
                }
            }
        }
    }
}

// ---------------------------------------------------------------------------
// K3: chamfer partial row-mins, pack fused, forced v_min3_f32 (R11, proven).
// grid (chunk 0..2, b 0..63, z 0..7: dir=z>>2, q=z&3); 1536 blocks = 6/CU.
// ---------------------------------------------------------------------------
__global__ __launch_bounds__(256) void chamfer_kernel(const float* __restrict__ pts3,
                                                      float* __restrict__ pmin) {
    const int chunk = blockIdx.x;
    const int b     = blockIdx.y;
    const int dir   = blockIdx.z >> 2;
    const int q     = blockIdx.z & 3;
    const int qa = dir * BB + b;
    const int qb = (1 - dir) * BB + b;
    const float* __restrict__ A3 = pts3 + (size_t)qa * JD;
    const float* __restrict__ B3 = pts3 + (size_t)qb * JD + q * (QCOLS * 3);

    __shared__ float4 Bs[QCOLS];
    const int tid = threadIdx.x;
    for (int i = tid; i < QCOLS; i += 256) {
        float x = B3[3 * i], y = B3[3 * i + 1], z = B3[3 * i + 2];
        Bs[i] = make_float4(-2.f * x, -2.f * y, -2.f * z, fmaf(x, x, fmaf(y, y, z * z)));
    }
    __syncthreads();

    int r0 = chunk * 512 + tid;
    int r1 = r0 + 256;
    float a0x = 0.f, a0y = 0.f, a0z = 0.f, a0w = 0.f;
    float a1x = 0.f, a1y = 0.f, a1z = 0.f, a1w = 0.f;
    if (r0 < NV) {
        a0x = A3[3 * r0]; a0y = A3[3 * r0 + 1]; a0z = A3[3 * r0 + 2];
        a0w = fmaf(a0x, a0x, fmaf(a0y, a0y, a0z * a0z));
    }
    if (r1 < NV) {
        a1x = A3[3 * r1]; a1y = A3[3 * r1 + 1]; a1z = A3[3 * r1 + 2];
        a1w = fmaf(a1x, a1x, fmaf(a1y, a1y, a1z * a1z));
    }
    float m0 = 1e30f, m1 = 1e30f;

#pragma unroll 2
    for (int m = 0; m < QCOLS; m += 2) {
        float4 b0 = Bs[m];
        float4 b1 = Bs[m + 1];
        float d00 = fmaf(b0.x, a0x, fmaf(b0.y, a0y, fmaf(b0.z, a0z, b0.w)));
        float d01 = fmaf(b1.x, a0x, fmaf(b1.y, a0y, fmaf(b1.z, a0z, b1.w)));
        asm("v_min3_f32 %0, %0, %1, %2" : "+v"(m0) : "v"(d00), "v"(d01));
        float d10 = fmaf(b0.x, a1x, fmaf(b0.y, a1y, fmaf(b0.z, a1z, b0.w)));
        float d11 = fmaf(b1.x, a1x, fmaf(b1.y, a1y, fmaf(b1.z, a1z, b1.w)));
        asm("v_min3_f32 %0, %0, %1, %2" : "+v"(m1) : "v"(d10), "v"(d11));
    }

    size_t base = (size_t)q * NROW + (size_t)qa * NV;
    if (r0 < NV) pmin[base + r0] = m0 + a0w;
    if (r1 < NV) pmin[base + r1] = m1 + a1w;
}

// ---------------------------------------------------------------------------
// K3b: combine 4 quarter-mins, sqrt, block sums -> fixed-point atomic;
// last block writes out. 256 blocks x 724 rows exact.
// ---------------------------------------------------------------------------
__global__ __launch_bounds__(256) void combine_kernel(const float* __restrict__ pmin,
                                                      unsigned long long* __restrict__ acc,
                                                      float* __restrict__ out) {
    const int base = blockIdx.x * 724;
    const int tid  = threadIdx.x;
    float s = 0.f;
#pragma unroll
    for (int it = 0; it < 3; ++it) {
        int idx = it * 256 + tid;
        if (idx < 724) {
            int g = base + idx;
            float v = fminf(fminf(pmin[g], pmin[g + NROW]),
                            fminf(pmin[g + 2 * NROW], pmin[g + 3 * NROW]));
            s += sqrtf(fmaxf(v, 1e-12f));
        }
    }
    s += __shfl_xor(s, 1);
    s += __shfl_xor(s, 2);
    s += __shfl_xor(s, 4);
    s += __shfl_xor(s, 8);
    s += __shfl_xor(s, 16);
    s += __shfl_xor(s, 32);
    __shared__ float wsum[4];
    if ((tid & 63) == 0) wsum[tid >> 6] = s;
    __syncthreads();
    if (tid == 0) {
        float bs = wsum[0] + wsum[1] + wsum[2] + wsum[3];
        unsigned long long qv = (unsigned long long)((double)bs * 16777216.0); // 2^24 fixed pt
        atomicAdd(acc, qv);
        __threadfence();
        unsigned long long done = atomicAdd(acc + 1, 1ull);
        if (done == 255) {
            __threadfence();
            unsigned long long total = atomicAdd(acc, 0ull);
            out[0] = (float)((double)total * (0x1p-24 / (64.0 * 1448.0)));
        }
    }
}

extern "C" void kernel_launch(void* const* d_in, const int* in_sizes, int n_in,
                              void* d_out, int out_size, void* d_ws, size_t ws_size,
                              hipStream_t stream) {
    const float* inp    = (const float*)d_in[0];
    const float* tgt    = (const float*)d_in[1];
    const int*   labels = (const int*)d_in[2];
    const float* muL    = (const float*)d_in[3];
    const float* deltaL = (const float*)d_in[4];
    const float* muR    = (const float*)d_in[5];
    const float* deltaR = (const float*)d_in[6];
    float* out = (float*)d_out;

    char* ws = (char*)d_ws;
    float* latT = (float*)ws;                                   // 128*256*4 = 131072 B
    float* pts3 = (float*)(ws + 131072);                        // 128*4344*4 = 2224128 B
    float* pmin = (float*)(ws + 131072 + 2224128);              // 4*185344*4 = 2965504 B
    unsigned long long* acc = (unsigned long long*)(ws + 131072 + 2224128 + 2965504);

    hipLaunchKernelGGL(pool_kernel, dim3(2048), dim3(256), 0, stream, inp, tgt, latT, acc);
    hipLaunchKernelGGL(decode_kernel, dim3(272, 2, 2), dim3(256), 0, stream,
                       latT, muL, deltaL, muR, deltaR, labels, pts3);
    hipLaunchKernelGGL(chamfer_kernel, dim3(3, 64, 8), dim3(256), 0, stream,
                       pts3, pmin);
    hipLaunchKernelGGL(combine_kernel, dim3(256), dim3(256), 0, stream, pmin, acc, out);
}

// Round 15
// 51.058 us; speedup vs baseline: 1.4217x; 1.4217x over previous
//
#include <hip/hip_runtime.h>

#define NV 1448
#define JD 4344    // 3*NV
#define CC 256
#define BB 64
#define QQ 128     // 2*BB
#define QCOLS 362  // NV/4, columns per chamfer block
#define NROW (2 * BB * NV)  // 185344 row-slots (dir x b x row)

typedef __bf16 bf16x8 __attribute__((ext_vector_type(8)));
typedef float  f32x4  __attribute__((ext_vector_type(4)));

__device__ __forceinline__ unsigned f2bf(float f) {   // fp32 -> bf16 bits, RNE
    unsigned u = __float_as_uint(f);
    return (u + 0x7FFFu + ((u >> 16) & 1u)) >> 16;
}

// ---------------------------------------------------------------------------
// K1: global average pool over H*W=64 -> latQb[q][c] (bf16), q = t*64+b.
// Thread 0 zeroes the combine accumulator.
// ---------------------------------------------------------------------------
__global__ __launch_bounds__(256) void pool_kernel(const float* __restrict__ inp,
                                                   const float* __restrict__ tgt,
                                                   unsigned short* __restrict__ latQb,
                                                   unsigned long long* __restrict__ acc) {
    int gid  = blockIdx.x * 256 + threadIdx.x;
    if (gid == 0) { acc[0] = 0ull; acc[1] = 0ull; }
    int lane = gid & 15;
    int row  = gid >> 4;                          // (t,b,c) flat, 32768 rows
    if (row >= 2 * BB * CC) return;
    int t  = row >> 14;                           // BB*CC = 16384
    int bc = row & 16383;
    const float* src = (t ? tgt : inp) + (size_t)bc * 64;
    float4 v = reinterpret_cast<const float4*>(src)[lane];
    float s = (v.x + v.y) + (v.z + v.w);
    s += __shfl_xor(s, 1);
    s += __shfl_xor(s, 2);
    s += __shfl_xor(s, 4);
    s += __shfl_xor(s, 8);
    if (lane == 0) {
        int b = bc >> 8, c = bc & 255;
        latQb[(size_t)(t * 64 + b) * CC + c] = (unsigned short)f2bf(s * (1.0f / 64.0f));
    }
}

// ---------------------------------------------------------------------------
// K2: decode GEMM via bf16 MFMA (16x16x32, fp32 accum).
// grid (68 jt of 64 j, 2 side, 4 q-quarter of 32 q) = 544 blocks x 256 thr.
// Stage: deltaB[64j][264k] bf16 (fp32->bf16 on the fly, rows coalesced 1KB
// per wave-iter) + latB[32q][264k] bf16 (b128 copies). Stride 264 (528B,
// 16B-aligned) spreads frag-read rows across banks.
// Wave w: j-strip of 16; hoists 8 B-frags (32 VGPR); 2 M-tiles x 8 MFMA.
// D layout (m89): col=lane&15 (=j), row=(lane>>4)*4+r (=q). mu added fp32.
// ---------------------------------------------------------------------------
__global__ __launch_bounds__(256) void decode_kernel(const unsigned short* __restrict__ latQb,
                                                     const float* __restrict__ muL,
                                                     const float* __restrict__ deltaL,
                                                     const float* __restrict__ muR,
                                                     const float* __restrict__ deltaR,
                                                     const int* __restrict__ labels,
                                                     float* __restrict__ pts3) {
    const int jt   = blockIdx.x;               // 68 tiles of 64 j
    const int side = blockIdx.y;
    const int qq   = blockIdx.z;               // q-quarter: 32 q
    const float* __restrict__ delta = side ? deltaR : deltaL;
    const float* __restrict__ mu    = side ? muR : muL;
    const int jb = jt * 64;
    const int q0 = qq * 32;
    const int tid  = threadIdx.x;
    const int w    = tid >> 6;
    const int lane = tid & 63;

    __shared__ unsigned short dB[64 * 264];    // [j][k] bf16
    __shared__ unsigned short lB[32 * 264];    // [q][k] bf16

    // stage deltaB: 4096 f4-chunks, 16/thread; wave reads full 1KB rows
#pragma unroll
    for (int i = 0; i < 16; ++i) {
        int idx = i * 256 + tid;
        int row = idx >> 6;                    // 0..63
        int ch  = idx & 63;                    // f4 chunk in row
        int j   = jb + row;
        unsigned u0 = 0, u1 = 0;
        if (j < JD) {
            float4 v = *reinterpret_cast<const float4*>(delta + (size_t)j * CC + ch * 4);
            u0 = f2bf(v.x) | (f2bf(v.y) << 16);
            u1 = f2bf(v.z) | (f2bf(v.w) << 16);
        }
        *reinterpret_cast<uint2*>(&dB[row * 264 + ch * 4]) = make_uint2(u0, u1);
    }
    // stage latB: 1024 16B-chunks, 4/thread
#pragma unroll
    for (int i = 0; i < 4; ++i) {
        int idx = i * 256 + tid;
        int row = idx >> 5;                    // 0..31
        int ch  = idx & 31;                    // 16B chunk
        *reinterpret_cast<uint4*>(&lB[row * 264 + ch * 8]) =
            *reinterpret_cast<const uint4*>(latQb + (size_t)(q0 + row) * CC + ch * 8);
    }
    __syncthreads();

    const int col  = lane & 15;                // j within strip / q-row within tile
    const int kgrp = lane >> 4;                // 0..3
    bf16x8 bfr[8];
#pragma unroll
    for (int ks = 0; ks < 8; ++ks)
        bfr[ks] = *reinterpret_cast<const bf16x8*>(&dB[(w * 16 + col) * 264 + ks * 32 + kgrp * 8]);

    int j = jb + w * 16 + col;
    float muv = (j < JD) ? mu[j] : 0.f;

#pragma unroll
    for (int mt = 0; mt < 2; ++mt) {
        f32x4 acc = {0.f, 0.f, 0.f, 0.f};
#pragma unroll
        for (int ks = 0; ks < 8; ++ks) {
            bf16x8 a = *reinterpret_cast<const bf16x8*>(&lB[(mt * 16 + col) * 264 + ks * 32 + kgrp * 8]);
            acc = __builtin_amdgcn_mfma_f32_16x16x32_bf16(a, bfr[ks], acc, 0, 0, 0);
        }
        if (j < JD) {
#pragma unroll
            for (int r = 0; r < 4; ++r) {
                int q = q0 + mt * 16 + kgrp * 4 + r;
                if (labels[q & 63] == side)
                    pts3[(size_t)q * JD + j] = acc[r] + muv;
            }
        }
    }
}

// ---------------------------------------------------------------------------
// K3: chamfer partial row-mins, pack fused, forced v_min3_f32 (R11, proven).
// grid (chunk 0..2, b 0..63, z 0..7: dir=z>>2, q=z&3); 1536 blocks = 6/CU.
// ---------------------------------------------------------------------------
__global__ __launch_bounds__(256) void chamfer_kernel(const float* __restrict__ pts3,
                                                      float* __restrict__ pmin) {
    const int chunk = blockIdx.x;
    const int b     = blockIdx.y;
    const int dir   = blockIdx.z >> 2;
    const int q     = blockIdx.z & 3;
    const int qa = dir * BB + b;
    const int qb = (1 - dir) * BB + b;
    const float* __restrict__ A3 = pts3 + (size_t)qa * JD;
    const float* __restrict__ B3 = pts3 + (size_t)qb * JD + q * (QCOLS * 3);

    __shared__ float4 Bs[QCOLS];
    const int tid = threadIdx.x;
    for (int i = tid; i < QCOLS; i += 256) {
        float x = B3[3 * i], y = B3[3 * i + 1], z = B3[3 * i + 2];
        Bs[i] = make_float4(-2.f * x, -2.f * y, -2.f * z, fmaf(x, x, fmaf(y, y, z * z)));
    }
    __syncthreads();

    int r0 = chunk * 512 + tid;
    int r1 = r0 + 256;
    float a0x = 0.f, a0y = 0.f, a0z = 0.f, a0w = 0.f;
    float a1x = 0.f, a1y = 0.f, a1z = 0.f, a1w = 0.f;
    if (r0 < NV) {
        a0x = A3[3 * r0]; a0y = A3[3 * r0 + 1]; a0z = A3[3 * r0 + 2];
        a0w = fmaf(a0x, a0x, fmaf(a0y, a0y, a0z * a0z));
    }
    if (r1 < NV) {
        a1x = A3[3 * r1]; a1y = A3[3 * r1 + 1]; a1z = A3[3 * r1 + 2];
        a1w = fmaf(a1x, a1x, fmaf(a1y, a1y, a1z * a1z));
    }
    float m0 = 1e30f, m1 = 1e30f;

#pragma unroll 2
    for (int m = 0; m < QCOLS; m += 2) {
        float4 b0 = Bs[m];
        float4 b1 = Bs[m + 1];
        float d00 = fmaf(b0.x, a0x, fmaf(b0.y, a0y, fmaf(b0.z, a0z, b0.w)));
        float d01 = fmaf(b1.x, a0x, fmaf(b1.y, a0y, fmaf(b1.z, a0z, b1.w)));
        asm("v_min3_f32 %0, %0, %1, %2" : "+v"(m0) : "v"(d00), "v"(d01));
        float d10 = fmaf(b0.x, a1x, fmaf(b0.y, a1y, fmaf(b0.z, a1z, b0.w)));
        float d11 = fmaf(b1.x, a1x, fmaf(b1.y, a1y, fmaf(b1.z, a1z, b1.w)));
        asm("v_min3_f32 %0, %0, %1, %2" : "+v"(m1) : "v"(d10), "v"(d11));
    }

    size_t base = (size_t)q * NROW + (size_t)qa * NV;
    if (r0 < NV) pmin[base + r0] = m0 + a0w;
    if (r1 < NV) pmin[base + r1] = m1 + a1w;
}

// ---------------------------------------------------------------------------
// K3b: combine 4 quarter-mins, sqrt, block sums -> fixed-point atomic;
// last block writes out. 256 blocks x 724 rows exact.
// ---------------------------------------------------------------------------
__global__ __launch_bounds__(256) void combine_kernel(const float* __restrict__ pmin,
                                                      unsigned long long* __restrict__ acc,
                                                      float* __restrict__ out) {
    const int base = blockIdx.x * 724;
    const int tid  = threadIdx.x;
    float s = 0.f;
#pragma unroll
    for (int it = 0; it < 3; ++it) {
        int idx = it * 256 + tid;
        if (idx < 724) {
            int g = base + idx;
            float v = fminf(fminf(pmin[g], pmin[g + NROW]),
                            fminf(pmin[g + 2 * NROW], pmin[g + 3 * NROW]));
            s += sqrtf(fmaxf(v, 1e-12f));
        }
    }
    s += __shfl_xor(s, 1);
    s += __shfl_xor(s, 2);
    s += __shfl_xor(s, 4);
    s += __shfl_xor(s, 8);
    s += __shfl_xor(s, 16);
    s += __shfl_xor(s, 32);
    __shared__ float wsum[4];
    if ((tid & 63) == 0) wsum[tid >> 6] = s;
    __syncthreads();
    if (tid == 0) {
        float bs = wsum[0] + wsum[1] + wsum[2] + wsum[3];
        unsigned long long qv = (unsigned long long)((double)bs * 16777216.0); // 2^24 fixed pt
        atomicAdd(acc, qv);
        __threadfence();
        unsigned long long done = atomicAdd(acc + 1, 1ull);
        if (done == 255) {
            __threadfence();
            unsigned long long total = atomicAdd(acc, 0ull);
            out[0] = (float)((double)total * (0x1p-24 / (64.0 * 1448.0)));
        }
    }
}

extern "C" void kernel_launch(void* const* d_in, const int* in_sizes, int n_in,
                              void* d_out, int out_size, void* d_ws, size_t ws_size,
                              hipStream_t stream) {
    const float* inp    = (const float*)d_in[0];
    const float* tgt    = (const float*)d_in[1];
    const int*   labels = (const int*)d_in[2];
    const float* muL    = (const float*)d_in[3];
    const float* deltaL = (const float*)d_in[4];
    const float* muR    = (const float*)d_in[5];
    const float* deltaR = (const float*)d_in[6];
    float* out = (float*)d_out;

    char* ws = (char*)d_ws;
    unsigned short* latQb = (unsigned short*)ws;                // 128*256*2 = 65536 B
    float* pts3 = (float*)(ws + 65536);                         // 128*4344*4 = 2224128 B
    float* pmin = (float*)(ws + 65536 + 2224128);               // 4*185344*4 = 2965504 B
    unsigned long long* acc = (unsigned long long*)(ws + 65536 + 2224128 + 2965504);

    hipLaunchKernelGGL(pool_kernel, dim3(2048), dim3(256), 0, stream, inp, tgt, latQb, acc);
    hipLaunchKernelGGL(decode_kernel, dim3(68, 2, 4), dim3(256), 0, stream,
                       latQb, muL, deltaL, muR, deltaR, labels, pts3);
    hipLaunchKernelGGL(chamfer_kernel, dim3(3, 64, 8), dim3(256), 0, stream,
                       pts3, pmin);
    hipLaunchKernelGGL(combine_kernel, dim3(256), dim3(256), 0, stream, pmin, acc, out);
}